// Round 8
// baseline (549.437 us; speedup 1.0000x reference)
//
#include <hip/hip_runtime.h>
#include <hip/hip_fp16.h>
#include <math.h>

#define M_TRAIN 100000
#define NQ 2048
#define DIM 128
#define KNN 16
#define NCLS 10

// Subsample for tau: every 16th train point; padded to 6272 = 49 * 128.
#define S_STRIDE 16
#define S_CNT (M_TRAIN / S_STRIDE)     // 6250
#define S_PAD 6272
#define SCH 49
#define SPC 128
#define TT 64
#define MQ 128
#define QSTR 136                       // LDS row stride in shorts (128 + 8 pad)

// Filter: one block = 64 queries x 128 train rows, one-shot (high TLP).
#define CAP 768
#define TBH 50176                      // rows per half (392 * 128)
#define NTR 128                        // train rows per block
#define NQT 64                         // queries per block
#define MARGIN 3.0f                    // proven in rounds 4-5/8
#define SLACK 7.0f                     // 2*(MARGIN + fp16 quant 0.25) rounded up

using bfrag = __attribute__((ext_vector_type(8))) short;
using cfrag = __attribute__((ext_vector_type(4))) float;

__device__ __forceinline__ bool better(float d1, int i1, float d2, int i2) {
    return (d1 < d2) || (d1 == d2 && i1 < i2);
}

__device__ __forceinline__ unsigned pack_bf16(float a, float b) {
    unsigned ua = __float_as_uint(a), ub = __float_as_uint(b);
    ua += 0x7fffu + ((ua >> 16) & 1u);   // RNE
    ub += 0x7fffu + ((ub >> 16) & 1u);
    return (ua >> 16) | (ub & 0xffff0000u);
}

__device__ __forceinline__ void gload_lds16(const void* g, void* l) {
    __builtin_amdgcn_global_load_lds(
        (const __attribute__((address_space(1))) unsigned int*)g,
        (__attribute__((address_space(3))) unsigned int*)l, 16, 0, 0);
}

// ---------------------------------------------------------------------------
// Kernel 0: squared norms, one wave per row. Also zeroes cnt (folded dispatch).
__global__ void knn_norms(const float* __restrict__ train,
                          const float* __restrict__ x,
                          float* __restrict__ t2, float* __restrict__ x2,
                          int* __restrict__ cnt) {
    int gid = blockIdx.x * blockDim.x + threadIdx.x;
    if (gid < NQ) cnt[gid] = 0;
    int gw = gid >> 6;
    int lane = threadIdx.x & 63;
    if (gw >= M_TRAIN + NQ) return;
    const float* r = (gw < M_TRAIN) ? (train + (size_t)gw * DIM)
                                    : (x + (size_t)(gw - M_TRAIN) * DIM);
    float a = r[lane];
    float b = r[lane + 64];
    float s = a * a + b * b;
    #pragma unroll
    for (int off = 32; off > 0; off >>= 1)
        s += __shfl_down(s, off, 64);
    if (lane == 0) {
        if (gw < M_TRAIN) t2[gw] = s; else x2[gw - M_TRAIN] = s;
    }
}

// ---------------------------------------------------------------------------
// Kernel 1: MFMA (bf16) approx-d2 over the stride-16 subsample -> fp16 matrix.
__global__ __launch_bounds__(256, 2)
void knn_sub_mfma(const float* __restrict__ x, const float* __restrict__ train,
                  const float* __restrict__ t2, const float* __restrict__ x2,
                  __half* __restrict__ dsub) {
    __shared__ short Q[MQ * QSTR];
    __shared__ short T[TT * QSTR];
    __shared__ float t2h[TT];
    int tid = threadIdx.x;
    int w = tid >> 6, lane = tid & 63;
    int rquad = lane >> 4, rcol = lane & 15;
    int qBase = blockIdx.y * MQ;
    int cBase = blockIdx.x * SPC;

    #pragma unroll
    for (int it = 0; it < 16; ++it) {
        int f = it * 256 + tid;
        int row = f >> 5, c4 = f & 31;
        float4 v = ((const float4*)x)[(size_t)(qBase + row) * (DIM / 4) + c4];
        uint2 p; p.x = pack_bf16(v.x, v.y); p.y = pack_bf16(v.z, v.w);
        *(uint2*)&Q[row * QSTR + c4 * 4] = p;
    }
    __syncthreads();

    float x2r[2][4];
    #pragma unroll
    for (int rt = 0; rt < 2; ++rt)
        #pragma unroll
        for (int reg = 0; reg < 4; ++reg)
            x2r[rt][reg] = x2[qBase + w * 32 + rt * 16 + rquad * 4 + reg];

    bfrag A[2][4];
    #pragma unroll
    for (int rt = 0; rt < 2; ++rt)
        #pragma unroll
        for (int ks = 0; ks < 4; ++ks) {
            int r = w * 32 + rt * 16 + rcol;
            A[rt][ks] = *(const bfrag*)&Q[r * QSTR + ks * 32 + rquad * 8];
        }

    const cfrag zero4 = {0.f, 0.f, 0.f, 0.f};
    for (int t = 0; t < 2; ++t) {
        __syncthreads();
        int sBase = cBase + t * TT;
        #pragma unroll
        for (int it = 0; it < 8; ++it) {
            int f = it * 256 + tid;
            int row = f >> 5, c4 = f & 31;
            int sj = sBase + row;
            bool ok = sj < S_CNT;
            float4 v = ok ? ((const float4*)train)[(size_t)sj * S_STRIDE * (DIM / 4) + c4]
                          : make_float4(0.f, 0.f, 0.f, 0.f);
            uint2 p; p.x = pack_bf16(v.x, v.y); p.y = pack_bf16(v.z, v.w);
            *(uint2*)&T[row * QSTR + c4 * 4] = p;
        }
        if (tid < TT) {
            int sj = sBase + tid;
            t2h[tid] = (sj < S_CNT) ? t2[(size_t)sj * S_STRIDE] : 1e30f;
        }
        __syncthreads();

        cfrag acc[2][4];
        #pragma unroll
        for (int ks = 0; ks < 4; ++ks) {
            bfrag B[4];
            #pragma unroll
            for (int ct = 0; ct < 4; ++ct) {
                int n = ct * 16 + rcol;
                B[ct] = *(const bfrag*)&T[n * QSTR + ks * 32 + rquad * 8];
            }
            #pragma unroll
            for (int rt = 0; rt < 2; ++rt)
                #pragma unroll
                for (int ct = 0; ct < 4; ++ct)
                    acc[rt][ct] = (ks == 0)
                        ? __builtin_amdgcn_mfma_f32_16x16x32_bf16(A[rt][0], B[ct], zero4, 0, 0, 0)
                        : __builtin_amdgcn_mfma_f32_16x16x32_bf16(A[rt][ks], B[ct], acc[rt][ct], 0, 0, 0);
        }

        float th[4];
        #pragma unroll
        for (int ct = 0; ct < 4; ++ct) th[ct] = t2h[ct * 16 + rcol];
        #pragma unroll
        for (int rt = 0; rt < 2; ++rt)
            #pragma unroll
            for (int ct = 0; ct < 4; ++ct)
                #pragma unroll
                for (int reg = 0; reg < 4; ++reg) {
                    float d2 = x2r[rt][reg] + th[ct] - 2.f * acc[rt][ct][reg];
                    int qrow = qBase + w * 32 + rt * 16 + rquad * 4 + reg;
                    int col = sBase + ct * 16 + rcol;
                    dsub[(size_t)qrow * S_PAD + col] = __float2half_rn(d2);
                }
    }
}

// ---------------------------------------------------------------------------
// Kernel 2: tau[q] = 16th-smallest value of dsub row q (values only).
__global__ __launch_bounds__(256)
void knn_select(const __half* __restrict__ dsub, float* __restrict__ tau) {
    __shared__ float wv[4];
    __shared__ int   wc[4];
    __shared__ float sv;
    __shared__ int   sc;
    int q = blockIdx.x, tid = threadIdx.x;
    int w = tid >> 6, lane = tid & 63;

    float bd[KNN];
    #pragma unroll
    for (int j = 0; j < KNN; ++j) bd[j] = 3.4e38f;
    for (int k = 0; k < 25; ++k) {
        int idx = k * 256 + tid;
        if (idx < S_PAD) {
            float v = __half2float(dsub[(size_t)q * S_PAD + idx]);
            if (v < bd[KNN - 1]) {
                bd[KNN - 1] = v;
                #pragma unroll
                for (int j = KNN - 1; j >= 1; --j)
                    if (bd[j] < bd[j - 1]) { float t = bd[j]; bd[j] = bd[j - 1]; bd[j - 1] = t; }
            }
        }
    }

    float last = 3.4e38f;
    for (int sel = 0; sel < KNN; ++sel) {
        float mv = bd[0]; int mj = 0;
        #pragma unroll
        for (int j = 1; j < KNN; ++j) if (bd[j] < mv) { mv = bd[j]; mj = j; }
        int mc = (tid << 4) | mj;
        #pragma unroll
        for (int off = 32; off > 0; off >>= 1) {
            float ov = __shfl_down(mv, off, 64);
            int   oc = __shfl_down(mc, off, 64);
            if (ov < mv) { mv = ov; mc = oc; }
        }
        if (lane == 0) { wv[w] = mv; wc[w] = mc; }
        __syncthreads();
        if (tid == 0) {
            float bv = wv[0]; int bc = wc[0];
            #pragma unroll
            for (int i = 1; i < 4; ++i) if (wv[i] < bv) { bv = wv[i]; bc = wc[i]; }
            sv = bv; sc = bc;
        }
        __syncthreads();
        last = sv;
        if (tid == (sc >> 4)) {
            int j0 = sc & 15;
            #pragma unroll
            for (int j = 0; j < KNN; ++j) if (j == j0) bd[j] = 3.4e38f;
        }
        __syncthreads();
    }
    if (tid == 0) tau[q] = last;
}

// ---------------------------------------------------------------------------
// Kernel 3: fp32 -> bf16 conversion of one train half (pad rows zero-filled).
// Train rows get the 16-byte-granule XOR swizzle baked into the WRITE so the
// filter's linear global_load_lds lands the swizzled layout in LDS.
// h0 launch carries 256 extra blocks that convert the 2048 query rows into a
// LINEAR bf16 buffer xb.
__global__ __launch_bounds__(256)
void knn_convert_bf16(const float* __restrict__ train,
                      unsigned int* __restrict__ tb, int rowBase,
                      const float* __restrict__ x,
                      unsigned int* __restrict__ xb) {
    int b = blockIdx.x;
    if (b >= (TBH * 32) / 256) {                   // x-conversion tail (h0 only)
        int i = (b - (TBH * 32) / 256) * 256 + threadIdx.x;   // 65536 threads
        int row = i >> 5, seg = i & 31;
        float4 v = ((const float4*)x)[(size_t)row * (DIM / 4) + seg];
        uint2 p; p.x = pack_bf16(v.x, v.y); p.y = pack_bf16(v.z, v.w);
        ((uint2*)xb)[(size_t)row * 32 + seg] = p;  // linear bf16[2048][128]
        return;
    }
    int i = b * 256 + threadIdx.x;                 // one thread per 4 floats
    int row = i >> 5, seg = i & 31;                // row in [0, TBH)
    int g = rowBase + row;
    float4 v = (g < M_TRAIN)
        ? ((const float4*)train)[(size_t)g * (DIM / 4) + seg]
        : make_float4(0.f, 0.f, 0.f, 0.f);
    uint2 p; p.x = pack_bf16(v.x, v.y); p.y = pack_bf16(v.z, v.w);
    int off = (seg * 8) ^ ((row & 7) << 4);        // swizzled byte offset in row
    *(uint2*)((char*)tb + (size_t)row * 256 + off) = p;
}

// ---------------------------------------------------------------------------
// Kernel 4: one-shot bf16 MFMA filter, WAVE-COLUMN-SPLIT + BARRIER-FREE.
// Round-8 diagnosis: SQ_LDS_BANK_CONFLICT constant 6.4M across rounds 0-7
// because every wave read ALL 128 tile rows (128KB ds_read per 32KB staged,
// 4x amplification) -> LDS pipe ~42us/dispatch was the invariant floor.
// Fix: wave w computes all 64 queries x ITS OWN 32 rows:
//   - B reads drop 32 -> 8 ds_read_b128 per wave (4x less LDS traffic)
//   - wave reads ONLY the LDS region it DMA'd -> NO __syncthreads at all;
//     one s_waitcnt vmcnt(0) per wave replaces the block-wide DMA drain
//   - A (all 64 queries, 16 frags) from xb global, L2-resident
// Epilogue: proven ballot/popcount, per (qt,reg): both ct-halves packed in
// one 32-bit mask; 16 popcount-atomics/wave, phase-split; x2/tau loaded
// AFTER the MFMA loop to keep peak VGPR under the (256,4) cap.
__global__ __launch_bounds__(256, 4)
void knn_filter10(const unsigned int* __restrict__ xbb,
                  const short* __restrict__ tbb,
                  const float* __restrict__ t2, const float* __restrict__ x2,
                  const float* __restrict__ tau, int pBase0,
                  int* __restrict__ buf_i, unsigned short* __restrict__ buf_h,
                  int* __restrict__ cnt) {
    __shared__ __align__(16) short T[NTR * DIM];   // 32768 B
    int tid = threadIdx.x;
    int w = tid >> 6, lane = tid & 63;
    int rquad = lane >> 4, rcol = lane & 15;

    // XCD-affinity decode (proven): same-tile q-blocks share an XCD.
    int bid = blockIdx.x;
    int xcd = bid & 7, r = bid >> 3;
    int qb = r & 31;
    int nch = xcd + 8 * (r >> 5);          // 0..391, tile index within half
    int qBase = qb * NQT;
    int tbase = pBase0 + nch * NTR;        // global train row base of tile

    // Stage: wave w DMAs ITS OWN rows w*32..w*32+31 (8 x 1KB, linear dest).
    const char* gsrc = (const char*)tbb + (size_t)nch * NTR * 256 + w * 8192 + lane * 16;
    char* ldst = (char*)T + w * 8192;
    #pragma unroll
    for (int i = 0; i < 8; ++i)
        gload_lds16(gsrc + i * 1024, ldst + i * 1024);

    // A-frags: ALL 64 queries (16 frags, 64 VGPR) from xb (overlaps DMA).
    bfrag A[4][4];
    #pragma unroll
    for (int qt = 0; qt < 4; ++qt) {
        const char* xrow = (const char*)xbb + (size_t)(qBase + qt * 16 + rcol) * 256;
        #pragma unroll
        for (int ks = 0; ks < 4; ++ks)
            A[qt][ks] = *(const bfrag*)(xrow + ks * 64 + rquad * 16);
    }
    // Norms for this wave's two 16-row groups.
    int row0 = tbase + w * 32 + rcol;      // ctl=0 row; ctl=1 is row0+16
    float th0 = 0.5f * t2[row0];
    float th1 = 0.5f * t2[row0 + 16];

    // Wave-local DMA drain: this wave reads only the LDS it wrote.
    asm volatile("s_waitcnt vmcnt(0)" ::: "memory");
    __builtin_amdgcn_sched_barrier(0);

    // B reads: 8 x ds_read_b128 from own region; col XOR'd with (rcol&7)<<4
    // (matches tb's pre-swizzle; row&7 == rcol&7 since 16|ctl*16, 32|w*32).
    int swz = (rcol & 7) << 4;
    const char* Tw = (const char*)T + w * 8192 + rcol * 256;

    const cfrag zero4 = {0.f, 0.f, 0.f, 0.f};
    cfrag acc[4][2];
    #pragma unroll
    for (int ks = 0; ks < 4; ++ks)
        #pragma unroll
        for (int ctl = 0; ctl < 2; ++ctl) {
            const bfrag B = *(const bfrag*)(Tw + ctl * 4096 + ((ks * 64 + rquad * 16) ^ swz));
            #pragma unroll
            for (int qt = 0; qt < 4; ++qt)
                acc[qt][ctl] = (ks == 0)
                    ? __builtin_amdgcn_mfma_f32_16x16x32_bf16(A[qt][0], B, zero4, 0, 0, 0)
                    : __builtin_amdgcn_mfma_f32_16x16x32_bf16(A[qt][ks], B, acc[qt][ctl], 0, 0, 0);
        }

    // ---- Epilogue (A dead; per-query params loaded now, float4) ----
    float x2s[4][4], tqs[4][4];
    #pragma unroll
    for (int qt = 0; qt < 4; ++qt) {
        int q0 = qBase + qt * 16 + rquad * 4;
        float4 xv = *(const float4*)&x2[q0];
        float4 tv = *(const float4*)&tau[q0];
        x2s[qt][0] = xv.x; x2s[qt][1] = xv.y; x2s[qt][2] = xv.z; x2s[qt][3] = xv.w;
        tqs[qt][0] = tv.x; tqs[qt][1] = tv.y; tqs[qt][2] = tv.z; tqs[qt][3] = tv.w;
    }

    // Phase 1: ballots -> packed masks (low16 = ctl0, high16 = ctl1).
    bool ok0 = row0 < M_TRAIN;
    bool ok1 = (row0 + 16) < M_TRAIN;
    unsigned gm[4][4];
    #pragma unroll
    for (int qt = 0; qt < 4; ++qt)
        #pragma unroll
        for (int reg = 0; reg < 4; ++reg) {
            float rc = 0.5f * (x2s[qt][reg] - tqs[qt][reg] - MARGIN);
            bool p0 = ok0 && (acc[qt][0][reg] >= rc + th0);
            bool p1 = ok1 && (acc[qt][1][reg] >= rc + th1);
            unsigned long long m0 = __ballot(p0);
            unsigned long long m1 = __ballot(p1);
            unsigned g0 = (unsigned)(m0 >> (rquad * 16)) & 0xFFFFu;
            unsigned g1 = (unsigned)(m1 >> (rquad * 16)) & 0xFFFFu;
            gm[qt][reg] = g0 | (g1 << 16);
        }

    // Phase 2: 16 independent popcount-atomics (leaders rcol==0), no uses.
    int baseR[4][4];
    #pragma unroll
    for (int qt = 0; qt < 4; ++qt)
        #pragma unroll
        for (int reg = 0; reg < 4; ++reg)
            if (rcol == 0)
                baseR[qt][reg] = atomicAdd(&cnt[qBase + qt * 16 + rquad * 4 + reg],
                                           __popc(gm[qt][reg]));

    // Phase 3: broadcast bases, prefix-popcount offsets, masked stores.
    int lsrc = lane & 48;                  // group leader (rcol==0 of my rquad)
    unsigned lb = 1u << rcol;
    #pragma unroll
    for (int qt = 0; qt < 4; ++qt)
        #pragma unroll
        for (int reg = 0; reg < 4; ++reg) {
            int b = __shfl(baseR[qt][reg], lsrc, 64);
            unsigned g = gm[qt][reg];
            unsigned g0 = g & 0xFFFFu, g1 = g >> 16;
            int q = qBase + qt * 16 + rquad * 4 + reg;
            if (g0 & lb) {
                int slot = b + __popc(g0 & (lb - 1));
                if (slot < CAP) {
                    buf_i[(size_t)q * CAP + slot] = row0;
                    float d2a = x2s[qt][reg] + 2.f * th0 - 2.f * acc[qt][0][reg];
                    buf_h[(size_t)q * CAP + slot] =
                        __half_as_ushort(__float2half_rn(d2a));
                }
            }
            if (g1 & lb) {
                int slot = b + __popc(g0) + __popc(g1 & (lb - 1));
                if (slot < CAP) {
                    buf_i[(size_t)q * CAP + slot] = row0 + 16;
                    float d2a = x2s[qt][reg] + 2.f * th1 - 2.f * acc[qt][1][reg];
                    buf_h[(size_t)q * CAP + slot] =
                        __half_as_ushort(__float2half_rn(d2a));
                }
            }
        }
}

// ---------------------------------------------------------------------------
// Kernel 5: approx-pruned exact re-rank + weighted vote.
// Phase A: 16th-smallest approx d2 (per-wave tournament + 64-wide rank merge)
// Phase B: compact candidates with d2a <= kth + SLACK (provably contains the
//          exact top-16 given |d2a - d2| <= MARGIN + fp16 quant)
// Phase C: exact fp32 gather ONLY for kept candidates (4-5x fewer rows)
// Phase D: fully parallel rank-scatter selection (no serial 16-round chain)
__global__ __launch_bounds__(256)
void knn_final(const float* __restrict__ x,
               const float* __restrict__ train,
               const float* __restrict__ t2v,
               const float* __restrict__ x2v,
               const int* __restrict__ buf_i,
               const __half* __restrict__ buf_h,
               const int* __restrict__ cnt,
               const int* __restrict__ labels,
               float* __restrict__ out) {
    __shared__ float sd[CAP];
    __shared__ int   si[CAP];
    __shared__ int   keep[CAP];
    __shared__ float wk[64];
    __shared__ int   kr[KNN];
    __shared__ float sthr;
    __shared__ int   smcnt;
    int q = blockIdx.x;
    int tid = threadIdx.x;
    int w = tid >> 6, lane = tid & 63;
    int grp = lane >> 4, sub = lane & 15;
    int n = cnt[q]; if (n > CAP) n = CAP;
    if (tid == 0) smcnt = 0;
    if (tid < KNN) kr[tid] = -1;

    // ---- Phase A: per-wave 16-smallest approx values over strided 192 ----
    float av[3];
    #pragma unroll
    for (int j = 0; j < 3; ++j) {
        int i = (w * 3 + j) * 64 + lane;
        av[j] = (i < n) ? __half2float(buf_h[(size_t)q * CAP + i]) : 3.4e38f;
    }
    for (int sel = 0; sel < KNN; ++sel) {
        float mv = av[0]; int mc = (lane << 2);
        if (av[1] < mv) { mv = av[1]; mc = (lane << 2) | 1; }
        if (av[2] < mv) { mv = av[2]; mc = (lane << 2) | 2; }
        #pragma unroll
        for (int off = 32; off > 0; off >>= 1) {
            float ov = __shfl_down(mv, off, 64);
            int   oc = __shfl_down(mc, off, 64);
            if (ov < mv || (ov == mv && oc < mc)) { mv = ov; mc = oc; }
        }
        mv = __shfl(mv, 0, 64);
        mc = __shfl(mc, 0, 64);
        if (lane == 0) wk[w * KNN + sel] = mv;
        if (lane == (mc >> 2)) {
            int j0 = mc & 3;
            if (j0 == 0) av[0] = 3.4e38f;
            else if (j0 == 1) av[1] = 3.4e38f;
            else av[2] = 3.4e38f;
        }
    }
    __syncthreads();
    // rank-merge of the 4x16 sorted lists -> global 16th smallest value
    if (tid < 64) {
        float v = wk[tid];
        int rank = 0;
        #pragma unroll 8
        for (int j = 0; j < 64; ++j) {
            float u = wk[j];
            if (u < v || (u == v && j < tid)) ++rank;
        }
        if (rank == KNN - 1) sthr = v + SLACK;
    }
    __syncthreads();
    float thr = sthr;

    // ---- Phase B: compact candidates within the window ----
    for (int i = tid; i < n; i += 256) {
        float h = __half2float(buf_h[(size_t)q * CAP + i]);
        if (h <= thr) {
            int p = atomicAdd(&smcnt, 1);
            keep[p] = buf_i[(size_t)q * CAP + i];
        }
    }
    __syncthreads();
    int m = smcnt;

    // ---- Phase C: exact fp32 distances for kept candidates ----
    const float4* xq = (const float4*)&x[(size_t)q * DIM + sub * 8];
    float4 qa = xq[0], qb = xq[1];
    float x2l = x2v[q];
    for (int base = 0; base < m; base += 16) {
        int i = base + w * 4 + grp;
        if (i < m) {
            int idx = keep[i];
            const float4* tr = (const float4*)&train[(size_t)idx * DIM + sub * 8];
            float4 ta = tr[0], tb4 = tr[1];
            float s = qa.x * ta.x + qa.y * ta.y + qa.z * ta.z + qa.w * ta.w
                    + qb.x * tb4.x + qb.y * tb4.y + qb.z * tb4.z + qb.w * tb4.w;
            s += __shfl_xor(s, 1, 64);
            s += __shfl_xor(s, 2, 64);
            s += __shfl_xor(s, 4, 64);
            s += __shfl_xor(s, 8, 64);
            if (sub == 0) { sd[i] = x2l + t2v[idx] - 2.f * s; si[i] = idx; }
        }
    }
    __syncthreads();

    // ---- Phase D: parallel rank-scatter selection (ranks unique: (d,idx)
    // total order). Each thread ranks its strided elements vs all m. ----
    for (int i = tid; i < m; i += 256) {
        float d = sd[i]; int ix = si[i];
        int rank = 0;
        for (int j = 0; j < m; ++j)
            if (better(sd[j], si[j], d, ix)) ++rank;
        if (rank < KNN) kr[rank] = i;
    }
    __syncthreads();

    // ---- Vote (m >= 16 structurally: all true top-16 pass filter+prune) ----
    if (tid == 0) {
        bool anyzero = false;
        float dist[KNN]; int kidx[KNN];
        #pragma unroll
        for (int j = 0; j < KNN; ++j) {
            int ii = kr[j];
            if (ii >= 0) {
                dist[j] = sqrtf(fmaxf(sd[ii], 0.f));
                kidx[j] = si[ii];
                if (dist[j] == 0.f) anyzero = true;
            } else { dist[j] = -1.f; kidx[j] = -1; }
        }
        float spr[NCLS];
        #pragma unroll
        for (int c = 0; c < NCLS; ++c) spr[c] = 0.f;
        #pragma unroll
        for (int j = 0; j < KNN; ++j) {
            int idxj = kidx[j];
            if (idxj < 0 || idxj >= M_TRAIN) continue;   // sentinel guard
            float wgt = anyzero ? (dist[j] == 0.f ? 1.f : 0.f) : 1.f / dist[j];
            spr[labels[idxj]] += wgt;
        }
        float s = 0.f;
        #pragma unroll
        for (int c = 0; c < NCLS; ++c) s += spr[c];
        if (s == 0.f) s = 1.f;
        float inv = 1.f / s;
        float best = -1.f; int bc = 0;
        #pragma unroll
        for (int c = 0; c < NCLS; ++c) {
            float pv = spr[c] * inv;
            out[NQ + (size_t)q * NCLS + c] = pv;
            if (pv > best) { best = pv; bc = c; }
        }
        out[q] = (float)bc;
    }
}

// ---------------------------------------------------------------------------
extern "C" void kernel_launch(void* const* d_in, const int* in_sizes, int n_in,
                              void* d_out, int out_size, void* d_ws, size_t ws_size,
                              hipStream_t stream) {
    const float* x      = (const float*)d_in[0];
    const float* train  = (const float*)d_in[1];
    const int*   labels = (const int*)d_in[2];
    float* out = (float*)d_out;

    // Byte-exact ws layout, IDENTICAL footprint (26,116,096 B):
    //   t2 401,408 | x2 8,192 | tau 8,192 | cnt 8,192 |
    //   region @425,984: dsub 25,690,112 (dead after knn_select)
    //     -> reused as tb 12,845,056 + buf_i 6,291,456 + xb 524,288
    //        + buf_h 3,145,728 (fp16 approx d2) -> ends at 22,806,528 < dsub end
    char* base = (char*)d_ws;
    float*  t2   = (float*)(base);
    float*  x2   = (float*)(base + 401408);
    float*  tau  = (float*)(base + 409600);
    int*    cnt  = (int*)  (base + 417792);
    char*   region = base + 425984;
    __half* dsub = (__half*)region;                        // 25,690,112 B
    unsigned int* tb = (unsigned int*)region;              // 12,845,056 B (aliases dsub)
    int*    bi   = (int*)(region + 12845056);              //  6,291,456 B
    unsigned int* xb = (unsigned int*)(region + 19136512); //    524,288 B
    __half* bh   = (__half*)(region + 19660800);           //  3,145,728 B

    int nrows = M_TRAIN + NQ;
    knn_norms<<<(nrows * 64 + 255) / 256, 256, 0, stream>>>(train, x, t2, x2, cnt);

    dim3 gs(SCH, NQ / MQ);
    knn_sub_mfma<<<gs, 256, 0, stream>>>(x, train, t2, x2, dsub);

    knn_select<<<NQ, 256, 0, stream>>>(dsub, tau);

    // dsub dead; process the train set in two bf16 halves over its storage.
    // h0's convert also packs x -> xb (256 extra blocks).
    for (int h = 0; h < 2; ++h) {
        int rowBase = h * TBH;
        int cgrid = (TBH * 32) / 256 + (h == 0 ? (NQ * 32) / 256 : 0);
        knn_convert_bf16<<<cgrid, 256, 0, stream>>>(train, tb, rowBase, x, xb);
        knn_filter10<<<(TBH / NTR) * (NQ / NQT), 256, 0, stream>>>(
            xb, (const short*)tb, t2, x2, tau, rowBase, bi, (unsigned short*)bh, cnt);
    }

    knn_final<<<NQ, 256, 0, stream>>>(x, train, t2, x2, bi, bh, cnt, labels, out);
}

// Round 9
// 389.875 us; speedup vs baseline: 1.4093x; 1.4093x over previous
//
#include <hip/hip_runtime.h>
#include <hip/hip_fp16.h>
#include <math.h>

#define M_TRAIN 100000
#define NQ 2048
#define DIM 128
#define KNN 16
#define NCLS 10

// Subsample for tau: every 16th train point; padded to 6272 = 49 * 128.
#define S_STRIDE 16
#define S_CNT (M_TRAIN / S_STRIDE)     // 6250
#define S_PAD 6272
#define SCH 49
#define SPC 128
#define TT 64
#define MQ 128
#define QSTR 136                       // LDS row stride in shorts (128 + 8 pad)

// Filter: one block = 64 queries x 128 train rows, one-shot (high TLP).
#define CAP 768
#define TBH 50176                      // rows per half (392 * 128)
#define NTR 128                        // train rows per block
#define NQT 64                         // queries per block
#define MARGIN 3.0f                    // proven in rounds 4-5/8
#define SLACK 7.0f                     // 2*(MARGIN + fp16 quant 0.25) rounded up

using bfrag = __attribute__((ext_vector_type(8))) short;
using cfrag = __attribute__((ext_vector_type(4))) float;

__device__ __forceinline__ bool better(float d1, int i1, float d2, int i2) {
    return (d1 < d2) || (d1 == d2 && i1 < i2);
}

__device__ __forceinline__ unsigned pack_bf16(float a, float b) {
    unsigned ua = __float_as_uint(a), ub = __float_as_uint(b);
    ua += 0x7fffu + ((ua >> 16) & 1u);   // RNE
    ub += 0x7fffu + ((ub >> 16) & 1u);
    return (ua >> 16) | (ub & 0xffff0000u);
}

__device__ __forceinline__ bfrag pack_bf16x8(const float* p) {
    union { unsigned u[4]; bfrag f; } r;
    r.u[0] = pack_bf16(p[0], p[1]);
    r.u[1] = pack_bf16(p[2], p[3]);
    r.u[2] = pack_bf16(p[4], p[5]);
    r.u[3] = pack_bf16(p[6], p[7]);
    return r.f;
}

__device__ __forceinline__ void gload_lds16(const void* g, void* l) {
    __builtin_amdgcn_global_load_lds(
        (const __attribute__((address_space(1))) unsigned int*)g,
        (__attribute__((address_space(3))) unsigned int*)l, 16, 0, 0);
}

// ---------------------------------------------------------------------------
// Kernel 0: squared norms, one wave per row. Also zeroes cnt (folded dispatch).
__global__ void knn_norms(const float* __restrict__ train,
                          const float* __restrict__ x,
                          float* __restrict__ t2, float* __restrict__ x2,
                          int* __restrict__ cnt) {
    int gid = blockIdx.x * blockDim.x + threadIdx.x;
    if (gid < NQ) cnt[gid] = 0;
    int gw = gid >> 6;
    int lane = threadIdx.x & 63;
    if (gw >= M_TRAIN + NQ) return;
    const float* r = (gw < M_TRAIN) ? (train + (size_t)gw * DIM)
                                    : (x + (size_t)(gw - M_TRAIN) * DIM);
    float a = r[lane];
    float b = r[lane + 64];
    float s = a * a + b * b;
    #pragma unroll
    for (int off = 32; off > 0; off >>= 1)
        s += __shfl_down(s, off, 64);
    if (lane == 0) {
        if (gw < M_TRAIN) t2[gw] = s; else x2[gw - M_TRAIN] = s;
    }
}

// ---------------------------------------------------------------------------
// Kernel 1: MFMA (bf16) approx-d2 over the stride-16 subsample -> fp16 matrix.
// Round-9 change: A-frags packed DIRECTLY in-register from fp32 x
// (pack_bf16x8, bit-identical to the old staged path) -> removes the 35 KB
// Q LDS array, the 16-iter block-wide pack loop and its barrier.
// LDS drops to ~17.7 KB -> 3 blocks/CU (784 blocks = 3.06/CU, tail-free).
__global__ __launch_bounds__(256, 3)
void knn_sub_mfma(const float* __restrict__ x, const float* __restrict__ train,
                  const float* __restrict__ t2, const float* __restrict__ x2,
                  __half* __restrict__ dsub) {
    __shared__ short T[TT * QSTR];
    __shared__ float t2h[TT];
    int tid = threadIdx.x;
    int w = tid >> 6, lane = tid & 63;
    int rquad = lane >> 4, rcol = lane & 15;
    int qBase = blockIdx.y * MQ;
    int cBase = blockIdx.x * SPC;

    // A-frags for this wave's 32 query rows, packed from fp32 x (L2-hot).
    bfrag A[2][4];
    #pragma unroll
    for (int rt = 0; rt < 2; ++rt) {
        int qr = qBase + w * 32 + rt * 16 + rcol;
        #pragma unroll
        for (int ks = 0; ks < 4; ++ks)
            A[rt][ks] = pack_bf16x8(&x[(size_t)qr * DIM + ks * 32 + rquad * 8]);
    }

    float x2r[2][4];
    #pragma unroll
    for (int rt = 0; rt < 2; ++rt)
        #pragma unroll
        for (int reg = 0; reg < 4; ++reg)
            x2r[rt][reg] = x2[qBase + w * 32 + rt * 16 + rquad * 4 + reg];

    const cfrag zero4 = {0.f, 0.f, 0.f, 0.f};
    for (int t = 0; t < 2; ++t) {
        __syncthreads();
        int sBase = cBase + t * TT;
        #pragma unroll
        for (int it = 0; it < 8; ++it) {
            int f = it * 256 + tid;
            int row = f >> 5, c4 = f & 31;
            int sj = sBase + row;
            bool ok = sj < S_CNT;
            float4 v = ok ? ((const float4*)train)[(size_t)sj * S_STRIDE * (DIM / 4) + c4]
                          : make_float4(0.f, 0.f, 0.f, 0.f);
            uint2 p; p.x = pack_bf16(v.x, v.y); p.y = pack_bf16(v.z, v.w);
            *(uint2*)&T[row * QSTR + c4 * 4] = p;
        }
        if (tid < TT) {
            int sj = sBase + tid;
            t2h[tid] = (sj < S_CNT) ? t2[(size_t)sj * S_STRIDE] : 1e30f;
        }
        __syncthreads();

        cfrag acc[2][4];
        #pragma unroll
        for (int ks = 0; ks < 4; ++ks) {
            bfrag B[4];
            #pragma unroll
            for (int ct = 0; ct < 4; ++ct) {
                int n = ct * 16 + rcol;
                B[ct] = *(const bfrag*)&T[n * QSTR + ks * 32 + rquad * 8];
            }
            #pragma unroll
            for (int rt = 0; rt < 2; ++rt)
                #pragma unroll
                for (int ct = 0; ct < 4; ++ct)
                    acc[rt][ct] = (ks == 0)
                        ? __builtin_amdgcn_mfma_f32_16x16x32_bf16(A[rt][0], B[ct], zero4, 0, 0, 0)
                        : __builtin_amdgcn_mfma_f32_16x16x32_bf16(A[rt][ks], B[ct], acc[rt][ct], 0, 0, 0);
        }

        float th[4];
        #pragma unroll
        for (int ct = 0; ct < 4; ++ct) th[ct] = t2h[ct * 16 + rcol];
        #pragma unroll
        for (int rt = 0; rt < 2; ++rt)
            #pragma unroll
            for (int ct = 0; ct < 4; ++ct)
                #pragma unroll
                for (int reg = 0; reg < 4; ++reg) {
                    float d2 = x2r[rt][reg] + th[ct] - 2.f * acc[rt][ct][reg];
                    int qrow = qBase + w * 32 + rt * 16 + rquad * 4 + reg;
                    int col = sBase + ct * 16 + rcol;
                    dsub[(size_t)qrow * S_PAD + col] = __float2half_rn(d2);
                }
    }
}

// ---------------------------------------------------------------------------
// Kernel 2: tau[q] = 16th-smallest value of dsub row q (values only).
// Round-9 change: per-thread sorted bd[16] (unchanged scan) then BARRIER-FREE
// per-wave tournament (bd[0] is lane-min; 6-shuffle reduce; winner shifts his
// sorted list down) -> 4 sorted 16-lists in LDS -> 64-wide rank merge.
// Replaces 16 serial block rounds with 32 __syncthreads. Same value exactly.
__global__ __launch_bounds__(256)
void knn_select(const __half* __restrict__ dsub, float* __restrict__ tau) {
    __shared__ float wk[64];
    int q = blockIdx.x, tid = threadIdx.x;
    int w = tid >> 6, lane = tid & 63;

    float bd[KNN];
    #pragma unroll
    for (int j = 0; j < KNN; ++j) bd[j] = 3.4e38f;
    for (int k = 0; k < 25; ++k) {
        int idx = k * 256 + tid;
        if (idx < S_PAD) {
            float v = __half2float(dsub[(size_t)q * S_PAD + idx]);
            if (v < bd[KNN - 1]) {
                bd[KNN - 1] = v;
                #pragma unroll
                for (int j = KNN - 1; j >= 1; --j)
                    if (bd[j] < bd[j - 1]) { float t = bd[j]; bd[j] = bd[j - 1]; bd[j - 1] = t; }
            }
        }
    }

    // Per-wave 16-smallest (sorted output), no barriers.
    #pragma unroll 1
    for (int sel = 0; sel < KNN; ++sel) {
        float mv = bd[0]; int ml = lane;
        #pragma unroll
        for (int off = 32; off > 0; off >>= 1) {
            float ov = __shfl_down(mv, off, 64);
            int   ol = __shfl_down(ml, off, 64);
            if (ov < mv || (ov == mv && ol < ml)) { mv = ov; ml = ol; }
        }
        mv = __shfl(mv, 0, 64);
        ml = __shfl(ml, 0, 64);
        if (lane == 0) wk[w * KNN + sel] = mv;
        if (lane == ml) {
            #pragma unroll
            for (int j = 0; j < KNN - 1; ++j) bd[j] = bd[j + 1];
            bd[KNN - 1] = 3.4e38f;
        }
    }
    __syncthreads();
    // Rank merge of 4 sorted 16-lists -> exact 16th smallest value.
    if (tid < 64) {
        float v = wk[tid];
        int rank = 0;
        #pragma unroll 8
        for (int j = 0; j < 64; ++j) {
            float u = wk[j];
            if (u < v || (u == v && j < tid)) ++rank;
        }
        if (rank == KNN - 1) tau[q] = v;
    }
}

// ---------------------------------------------------------------------------
// Kernel 3: fp32 -> bf16 conversion of one train half (pad rows zero-filled).
// Train rows get the 16-byte-granule XOR swizzle baked into the WRITE so the
// filter's linear global_load_lds lands the swizzled layout in LDS.
// h0 launch carries 256 extra blocks that convert the 2048 query rows into a
// LINEAR bf16 buffer xb.
__global__ __launch_bounds__(256)
void knn_convert_bf16(const float* __restrict__ train,
                      unsigned int* __restrict__ tb, int rowBase,
                      const float* __restrict__ x,
                      unsigned int* __restrict__ xb) {
    int b = blockIdx.x;
    if (b >= (TBH * 32) / 256) {                   // x-conversion tail (h0 only)
        int i = (b - (TBH * 32) / 256) * 256 + threadIdx.x;   // 65536 threads
        int row = i >> 5, seg = i & 31;
        float4 v = ((const float4*)x)[(size_t)row * (DIM / 4) + seg];
        uint2 p; p.x = pack_bf16(v.x, v.y); p.y = pack_bf16(v.z, v.w);
        ((uint2*)xb)[(size_t)row * 32 + seg] = p;  // linear bf16[2048][128]
        return;
    }
    int i = b * 256 + threadIdx.x;                 // one thread per 4 floats
    int row = i >> 5, seg = i & 31;                // row in [0, TBH)
    int g = rowBase + row;
    float4 v = (g < M_TRAIN)
        ? ((const float4*)train)[(size_t)g * (DIM / 4) + seg]
        : make_float4(0.f, 0.f, 0.f, 0.f);
    uint2 p; p.x = pack_bf16(v.x, v.y); p.y = pack_bf16(v.z, v.w);
    int off = (seg * 8) ^ ((row & 7) << 4);        // swizzled byte offset in row
    *(uint2*)((char*)tb + (size_t)row * 256 + off) = p;
}

// ---------------------------------------------------------------------------
// Kernel 4: one-shot bf16 MFMA filter (64 queries x 128 train rows, K=128).
// Round-9: filter7 (95us, VALUBusy 73%) minus the re-ballot storm: ballots
// issued ONCE in phase A and stored as PACKED masks gmp[4][4] (2 cts/word,
// 16 VGPRs -- not filter6's gm32+ph16 that spilled). acc stays live; d2a
// computed lazily at store time (filter7-proven). Peak liveness ~75 VGPR.
__global__ __launch_bounds__(256, 4)
void knn_filter11(const unsigned int* __restrict__ xbb,
                  const short* __restrict__ tbb,
                  const float* __restrict__ t2, const float* __restrict__ x2,
                  const float* __restrict__ tau, int pBase0,
                  int* __restrict__ buf_i, unsigned short* __restrict__ buf_h,
                  int* __restrict__ cnt) {
    __shared__ __align__(16) short T[NTR * DIM];   // 32768 B, single buffer
    int tid = threadIdx.x;
    int w = tid >> 6, lane = tid & 63;
    int rquad = lane >> 4, rcol = lane & 15;

    // XCD-affinity decode (proven): same-tile q-blocks share an XCD.
    int bid = blockIdx.x;
    int xcd = bid & 7, r = bid >> 3;
    int qb = r & 31;
    int nch = xcd + 8 * (r >> 5);          // 0..391, tile index within half
    int qBase = qb * NQT;
    int tbase = pBase0 + nch * NTR;        // global train row base of tile

    // Stage tile: wave w DMAs rows w*32..w*32+31 (8 x 1KB), linear dest.
    const char* gsrc = (const char*)tbb + (size_t)nch * NTR * 256 + w * 8192 + lane * 16;
    char* ldst = (char*)T + w * 8192;
    #pragma unroll
    for (int i = 0; i < 8; ++i)
        gload_lds16(gsrc + i * 1024, ldst + i * 1024);

    // A-frags: direct bf16 loads from xb (overlaps DMA latency).
    bfrag A[4];
    int qrow = qBase + w * 16 + rcol;
    const char* xrow = (const char*)xbb + (size_t)qrow * 256;
    #pragma unroll
    for (int ks = 0; ks < 4; ++ks)
        A[ks] = *(const bfrag*)(xrow + ks * 64 + rquad * 16);

    float RC[4], x2q[4];
    #pragma unroll
    for (int reg = 0; reg < 4; ++reg) {
        int q = qBase + w * 16 + rquad * 4 + reg;
        x2q[reg] = x2[q];
        RC[reg] = 0.5f * (x2q[reg] - tau[q] - MARGIN);
    }
    float th[8];
    #pragma unroll
    for (int ct = 0; ct < 8; ++ct)
        th[ct] = 0.5f * t2[tbase + ct * 16 + rcol];
    __syncthreads();                       // drains DMA (vmcnt) + joins waves

    // Swizzled B reads: row = ct*16+rcol; byte col XOR'd with (rcol&7)<<4.
    int swz = (rcol & 7) << 4;
    int cs[4];
    #pragma unroll
    for (int ks = 0; ks < 4; ++ks)
        cs[ks] = (ks * 64 + rquad * 16) ^ swz;

    const cfrag zero4 = {0.f, 0.f, 0.f, 0.f};
    cfrag acc[8];
    #pragma unroll
    for (int ks = 0; ks < 4; ++ks)
        #pragma unroll
        for (int ct = 0; ct < 8; ++ct) {
            const bfrag B = *(const bfrag*)((const char*)T + (ct * 16 + rcol) * 256 + cs[ks]);
            acc[ct] = (ks == 0)
                ? __builtin_amdgcn_mfma_f32_16x16x32_bf16(A[0], B, zero4, 0, 0, 0)
                : __builtin_amdgcn_mfma_f32_16x16x32_bf16(A[ks], B, acc[ct], 0, 0, 0);
        }

    // ---- Phase A: ballots ONCE -> packed masks (lo16 = ct even, hi16 = odd)
    unsigned gmp[4][4];
    int tot[4];
    #pragma unroll
    for (int reg = 0; reg < 4; ++reg) {
        int t = 0;
        #pragma unroll
        for (int cp = 0; cp < 4; ++cp) {
            int c0 = cp * 2, c1 = cp * 2 + 1;
            bool p0 = (acc[c0][reg] >= RC[reg] + th[c0]) && (tbase + c0 * 16 + rcol < M_TRAIN);
            bool p1 = (acc[c1][reg] >= RC[reg] + th[c1]) && (tbase + c1 * 16 + rcol < M_TRAIN);
            unsigned long long m0 = __ballot(p0);
            unsigned long long m1 = __ballot(p1);
            unsigned g = ((unsigned)(m0 >> (rquad * 16)) & 0xFFFFu)
                       | (((unsigned)(m1 >> (rquad * 16)) & 0xFFFFu) << 16);
            gmp[reg][cp] = g;
            t += __popc(g);
        }
        tot[reg] = t;
    }
    // ---- Phase B: 4 independent atomics, no intervening use of results ----
    int baseR[4];
    #pragma unroll
    for (int reg = 0; reg < 4; ++reg) {
        int q = qBase + w * 16 + rquad * 4 + reg;
        if (rcol == 0) baseR[reg] = atomicAdd(&cnt[q], tot[reg]);
    }
    // ---- Phase C: broadcast bases, unpack stored masks, prefix stores ----
    int lsrc = lane & 48;                  // group leader lane (rcol==0)
    unsigned lb = 1u << rcol;
    #pragma unroll
    for (int reg = 0; reg < 4; ++reg) {
        int q = qBase + w * 16 + rquad * 4 + reg;
        int b = __shfl(baseR[reg], lsrc, 64);
        int off = 0;
        #pragma unroll
        for (int cp = 0; cp < 4; ++cp) {
            unsigned g = gmp[reg][cp];
            unsigned g0 = g & 0xFFFFu, g1 = g >> 16;
            if (g0 & lb) {
                int slot = b + off + __popc(g0 & (lb - 1));
                if (slot < CAP) {
                    buf_i[(size_t)q * CAP + slot] = tbase + cp * 32 + rcol;
                    float d2a = x2q[reg] + 2.f * th[cp * 2] - 2.f * acc[cp * 2][reg];
                    buf_h[(size_t)q * CAP + slot] =
                        __half_as_ushort(__float2half_rn(d2a));
                }
            }
            off += __popc(g0);
            if (g1 & lb) {
                int slot = b + off + __popc(g1 & (lb - 1));
                if (slot < CAP) {
                    buf_i[(size_t)q * CAP + slot] = tbase + cp * 32 + 16 + rcol;
                    float d2a = x2q[reg] + 2.f * th[cp * 2 + 1] - 2.f * acc[cp * 2 + 1][reg];
                    buf_h[(size_t)q * CAP + slot] =
                        __half_as_ushort(__float2half_rn(d2a));
                }
            }
            off += __popc(g1);
        }
    }
}

// ---------------------------------------------------------------------------
// Kernel 5: approx-pruned exact re-rank + weighted vote.
// Phase A: 16th-smallest approx d2 (per-wave tournament + 64-wide rank merge)
// Phase B: compact candidates with d2a <= kth + SLACK (provably contains the
//          exact top-16 given |d2a - d2| <= MARGIN + fp16 quant)
// Phase C: exact fp32 gather ONLY for kept candidates (4-5x fewer rows)
// Phase D: fully parallel rank-scatter selection (no serial 16-round chain)
__global__ __launch_bounds__(256)
void knn_final(const float* __restrict__ x,
               const float* __restrict__ train,
               const float* __restrict__ t2v,
               const float* __restrict__ x2v,
               const int* __restrict__ buf_i,
               const __half* __restrict__ buf_h,
               const int* __restrict__ cnt,
               const int* __restrict__ labels,
               float* __restrict__ out) {
    __shared__ float sd[CAP];
    __shared__ int   si[CAP];
    __shared__ int   keep[CAP];
    __shared__ float wk[64];
    __shared__ int   kr[KNN];
    __shared__ float sthr;
    __shared__ int   smcnt;
    int q = blockIdx.x;
    int tid = threadIdx.x;
    int w = tid >> 6, lane = tid & 63;
    int grp = lane >> 4, sub = lane & 15;
    int n = cnt[q]; if (n > CAP) n = CAP;
    if (tid == 0) smcnt = 0;
    if (tid < KNN) kr[tid] = -1;

    // ---- Phase A: per-wave 16-smallest approx values over strided 192 ----
    float av[3];
    #pragma unroll
    for (int j = 0; j < 3; ++j) {
        int i = (w * 3 + j) * 64 + lane;
        av[j] = (i < n) ? __half2float(buf_h[(size_t)q * CAP + i]) : 3.4e38f;
    }
    for (int sel = 0; sel < KNN; ++sel) {
        float mv = av[0]; int mc = (lane << 2);
        if (av[1] < mv) { mv = av[1]; mc = (lane << 2) | 1; }
        if (av[2] < mv) { mv = av[2]; mc = (lane << 2) | 2; }
        #pragma unroll
        for (int off = 32; off > 0; off >>= 1) {
            float ov = __shfl_down(mv, off, 64);
            int   oc = __shfl_down(mc, off, 64);
            if (ov < mv || (ov == mv && oc < mc)) { mv = ov; mc = oc; }
        }
        mv = __shfl(mv, 0, 64);
        mc = __shfl(mc, 0, 64);
        if (lane == 0) wk[w * KNN + sel] = mv;
        if (lane == (mc >> 2)) {
            int j0 = mc & 3;
            if (j0 == 0) av[0] = 3.4e38f;
            else if (j0 == 1) av[1] = 3.4e38f;
            else av[2] = 3.4e38f;
        }
    }
    __syncthreads();
    // rank-merge of the 4x16 sorted lists -> global 16th smallest value
    if (tid < 64) {
        float v = wk[tid];
        int rank = 0;
        #pragma unroll 8
        for (int j = 0; j < 64; ++j) {
            float u = wk[j];
            if (u < v || (u == v && j < tid)) ++rank;
        }
        if (rank == KNN - 1) sthr = v + SLACK;
    }
    __syncthreads();
    float thr = sthr;

    // ---- Phase B: compact candidates within the window ----
    for (int i = tid; i < n; i += 256) {
        float h = __half2float(buf_h[(size_t)q * CAP + i]);
        if (h <= thr) {
            int p = atomicAdd(&smcnt, 1);
            keep[p] = buf_i[(size_t)q * CAP + i];
        }
    }
    __syncthreads();
    int m = smcnt;

    // ---- Phase C: exact fp32 distances for kept candidates ----
    const float4* xq = (const float4*)&x[(size_t)q * DIM + sub * 8];
    float4 qa = xq[0], qb = xq[1];
    float x2l = x2v[q];
    for (int base = 0; base < m; base += 16) {
        int i = base + w * 4 + grp;
        if (i < m) {
            int idx = keep[i];
            const float4* tr = (const float4*)&train[(size_t)idx * DIM + sub * 8];
            float4 ta = tr[0], tb4 = tr[1];
            float s = qa.x * ta.x + qa.y * ta.y + qa.z * ta.z + qa.w * ta.w
                    + qb.x * tb4.x + qb.y * tb4.y + qb.z * tb4.z + qb.w * tb4.w;
            s += __shfl_xor(s, 1, 64);
            s += __shfl_xor(s, 2, 64);
            s += __shfl_xor(s, 4, 64);
            s += __shfl_xor(s, 8, 64);
            if (sub == 0) { sd[i] = x2l + t2v[idx] - 2.f * s; si[i] = idx; }
        }
    }
    __syncthreads();

    // ---- Phase D: parallel rank-scatter selection (ranks unique: (d,idx)
    // total order). Each thread ranks its strided elements vs all m. ----
    for (int i = tid; i < m; i += 256) {
        float d = sd[i]; int ix = si[i];
        int rank = 0;
        for (int j = 0; j < m; ++j)
            if (better(sd[j], si[j], d, ix)) ++rank;
        if (rank < KNN) kr[rank] = i;
    }
    __syncthreads();

    // ---- Vote (m >= 16 structurally: all true top-16 pass filter+prune) ----
    if (tid == 0) {
        bool anyzero = false;
        float dist[KNN]; int kidx[KNN];
        #pragma unroll
        for (int j = 0; j < KNN; ++j) {
            int ii = kr[j];
            if (ii >= 0) {
                dist[j] = sqrtf(fmaxf(sd[ii], 0.f));
                kidx[j] = si[ii];
                if (dist[j] == 0.f) anyzero = true;
            } else { dist[j] = -1.f; kidx[j] = -1; }
        }
        float spr[NCLS];
        #pragma unroll
        for (int c = 0; c < NCLS; ++c) spr[c] = 0.f;
        #pragma unroll
        for (int j = 0; j < KNN; ++j) {
            int idxj = kidx[j];
            if (idxj < 0 || idxj >= M_TRAIN) continue;   // sentinel guard
            float wgt = anyzero ? (dist[j] == 0.f ? 1.f : 0.f) : 1.f / dist[j];
            spr[labels[idxj]] += wgt;
        }
        float s = 0.f;
        #pragma unroll
        for (int c = 0; c < NCLS; ++c) s += spr[c];
        if (s == 0.f) s = 1.f;
        float inv = 1.f / s;
        float best = -1.f; int bc = 0;
        #pragma unroll
        for (int c = 0; c < NCLS; ++c) {
            float pv = spr[c] * inv;
            out[NQ + (size_t)q * NCLS + c] = pv;
            if (pv > best) { best = pv; bc = c; }
        }
        out[q] = (float)bc;
    }
}

// ---------------------------------------------------------------------------
extern "C" void kernel_launch(void* const* d_in, const int* in_sizes, int n_in,
                              void* d_out, int out_size, void* d_ws, size_t ws_size,
                              hipStream_t stream) {
    const float* x      = (const float*)d_in[0];
    const float* train  = (const float*)d_in[1];
    const int*   labels = (const int*)d_in[2];
    float* out = (float*)d_out;

    // Byte-exact ws layout, IDENTICAL footprint (26,116,096 B):
    //   t2 401,408 | x2 8,192 | tau 8,192 | cnt 8,192 |
    //   region @425,984: dsub 25,690,112 (dead after knn_select)
    //     -> reused as tb 12,845,056 + buf_i 6,291,456 + xb 524,288
    //        + buf_h 3,145,728 (fp16 approx d2) -> ends at 22,806,528 < dsub end
    char* base = (char*)d_ws;
    float*  t2   = (float*)(base);
    float*  x2   = (float*)(base + 401408);
    float*  tau  = (float*)(base + 409600);
    int*    cnt  = (int*)  (base + 417792);
    char*   region = base + 425984;
    __half* dsub = (__half*)region;                        // 25,690,112 B
    unsigned int* tb = (unsigned int*)region;              // 12,845,056 B (aliases dsub)
    int*    bi   = (int*)(region + 12845056);              //  6,291,456 B
    unsigned int* xb = (unsigned int*)(region + 19136512); //    524,288 B
    __half* bh   = (__half*)(region + 19660800);           //  3,145,728 B

    int nrows = M_TRAIN + NQ;
    knn_norms<<<(nrows * 64 + 255) / 256, 256, 0, stream>>>(train, x, t2, x2, cnt);

    dim3 gs(SCH, NQ / MQ);
    knn_sub_mfma<<<gs, 256, 0, stream>>>(x, train, t2, x2, dsub);

    knn_select<<<NQ, 256, 0, stream>>>(dsub, tau);

    // dsub dead; process the train set in two bf16 halves over its storage.
    // h0's convert also packs x -> xb (256 extra blocks).
    for (int h = 0; h < 2; ++h) {
        int rowBase = h * TBH;
        int cgrid = (TBH * 32) / 256 + (h == 0 ? (NQ * 32) / 256 : 0);
        knn_convert_bf16<<<cgrid, 256, 0, stream>>>(train, tb, rowBase, x, xb);
        knn_filter11<<<(TBH / NTR) * (NQ / NQT), 256, 0, stream>>>(
            xb, (const short*)tb, t2, x2, tau, rowBase, bi, (unsigned short*)bh, cnt);
    }

    knn_final<<<NQ, 256, 0, stream>>>(x, train, t2, x2, bi, bh, cnt, labels, out);
}

// Round 11
// 384.863 us; speedup vs baseline: 1.4276x; 1.0130x over previous
//
#include <hip/hip_runtime.h>
#include <hip/hip_fp16.h>
#include <math.h>

#define M_TRAIN 100000
#define NQ 2048
#define DIM 128
#define KNN 16
#define NCLS 10

// Subsample for tau: every 16th train point; padded to 6272 = 49 * 128.
#define S_STRIDE 16
#define S_CNT (M_TRAIN / S_STRIDE)     // 6250
#define S_PAD 6272
#define SCH 49
#define SPC 128
#define TT 64
#define MQ 128
#define QSTR 136                       // LDS row stride in shorts (128 + 8 pad)

// Filter: one block = 64 queries x 128 train rows, one-shot (high TLP).
#define CAP 768
#define TBH 50176                      // rows per half (392 * 128)
#define NTR 128                        // train rows per block
#define NQT 64                         // queries per block
#define MARGIN 3.0f                    // proven in rounds 4-5/8
#define SLACK 7.0f                     // 2*(MARGIN + fp16 quant 0.25) rounded up

using bfrag = __attribute__((ext_vector_type(8))) short;
using cfrag = __attribute__((ext_vector_type(4))) float;

__device__ __forceinline__ bool better(float d1, int i1, float d2, int i2) {
    return (d1 < d2) || (d1 == d2 && i1 < i2);
}

__device__ __forceinline__ unsigned pack_bf16(float a, float b) {
    unsigned ua = __float_as_uint(a), ub = __float_as_uint(b);
    ua += 0x7fffu + ((ua >> 16) & 1u);   // RNE
    ub += 0x7fffu + ((ub >> 16) & 1u);
    return (ua >> 16) | (ub & 0xffff0000u);
}

__device__ __forceinline__ bfrag pack_bf16x8(const float* p) {
    union { unsigned u[4]; bfrag f; } r;
    r.u[0] = pack_bf16(p[0], p[1]);
    r.u[1] = pack_bf16(p[2], p[3]);
    r.u[2] = pack_bf16(p[4], p[5]);
    r.u[3] = pack_bf16(p[6], p[7]);
    return r.f;
}

__device__ __forceinline__ void gload_lds16(const void* g, void* l) {
    __builtin_amdgcn_global_load_lds(
        (const __attribute__((address_space(1))) unsigned int*)g,
        (__attribute__((address_space(3))) unsigned int*)l, 16, 0, 0);
}

// ---------------------------------------------------------------------------
// Kernel 0: squared norms, one wave per row. Also zeroes cnt (folded dispatch).
__global__ void knn_norms(const float* __restrict__ train,
                          const float* __restrict__ x,
                          float* __restrict__ t2, float* __restrict__ x2,
                          int* __restrict__ cnt) {
    int gid = blockIdx.x * blockDim.x + threadIdx.x;
    if (gid < NQ) cnt[gid] = 0;
    int gw = gid >> 6;
    int lane = threadIdx.x & 63;
    if (gw >= M_TRAIN + NQ) return;
    const float* r = (gw < M_TRAIN) ? (train + (size_t)gw * DIM)
                                    : (x + (size_t)(gw - M_TRAIN) * DIM);
    float a = r[lane];
    float b = r[lane + 64];
    float s = a * a + b * b;
    #pragma unroll
    for (int off = 32; off > 0; off >>= 1)
        s += __shfl_down(s, off, 64);
    if (lane == 0) {
        if (gw < M_TRAIN) t2[gw] = s; else x2[gw - M_TRAIN] = s;
    }
}

// ---------------------------------------------------------------------------
// Kernel 1: MFMA (bf16) approx-d2 over the stride-16 subsample -> fp16 matrix.
// A-frags packed in-register from fp32 x (bit-identical); no Q LDS staging.
__global__ __launch_bounds__(256, 3)
void knn_sub_mfma(const float* __restrict__ x, const float* __restrict__ train,
                  const float* __restrict__ t2, const float* __restrict__ x2,
                  __half* __restrict__ dsub) {
    __shared__ short T[TT * QSTR];
    __shared__ float t2h[TT];
    int tid = threadIdx.x;
    int w = tid >> 6, lane = tid & 63;
    int rquad = lane >> 4, rcol = lane & 15;
    int qBase = blockIdx.y * MQ;
    int cBase = blockIdx.x * SPC;

    // A-frags for this wave's 32 query rows, packed from fp32 x (L2-hot).
    bfrag A[2][4];
    #pragma unroll
    for (int rt = 0; rt < 2; ++rt) {
        int qr = qBase + w * 32 + rt * 16 + rcol;
        #pragma unroll
        for (int ks = 0; ks < 4; ++ks)
            A[rt][ks] = pack_bf16x8(&x[(size_t)qr * DIM + ks * 32 + rquad * 8]);
    }

    float x2r[2][4];
    #pragma unroll
    for (int rt = 0; rt < 2; ++rt)
        #pragma unroll
        for (int reg = 0; reg < 4; ++reg)
            x2r[rt][reg] = x2[qBase + w * 32 + rt * 16 + rquad * 4 + reg];

    const cfrag zero4 = {0.f, 0.f, 0.f, 0.f};
    for (int t = 0; t < 2; ++t) {
        __syncthreads();
        int sBase = cBase + t * TT;
        #pragma unroll
        for (int it = 0; it < 8; ++it) {
            int f = it * 256 + tid;
            int row = f >> 5, c4 = f & 31;
            int sj = sBase + row;
            bool ok = sj < S_CNT;
            float4 v = ok ? ((const float4*)train)[(size_t)sj * S_STRIDE * (DIM / 4) + c4]
                          : make_float4(0.f, 0.f, 0.f, 0.f);
            uint2 p; p.x = pack_bf16(v.x, v.y); p.y = pack_bf16(v.z, v.w);
            *(uint2*)&T[row * QSTR + c4 * 4] = p;
        }
        if (tid < TT) {
            int sj = sBase + tid;
            t2h[tid] = (sj < S_CNT) ? t2[(size_t)sj * S_STRIDE] : 1e30f;
        }
        __syncthreads();

        cfrag acc[2][4];
        #pragma unroll
        for (int ks = 0; ks < 4; ++ks) {
            bfrag B[4];
            #pragma unroll
            for (int ct = 0; ct < 4; ++ct) {
                int n = ct * 16 + rcol;
                B[ct] = *(const bfrag*)&T[n * QSTR + ks * 32 + rquad * 8];
            }
            #pragma unroll
            for (int rt = 0; rt < 2; ++rt)
                #pragma unroll
                for (int ct = 0; ct < 4; ++ct)
                    acc[rt][ct] = (ks == 0)
                        ? __builtin_amdgcn_mfma_f32_16x16x32_bf16(A[rt][0], B[ct], zero4, 0, 0, 0)
                        : __builtin_amdgcn_mfma_f32_16x16x32_bf16(A[rt][ks], B[ct], acc[rt][ct], 0, 0, 0);
        }

        float th[4];
        #pragma unroll
        for (int ct = 0; ct < 4; ++ct) th[ct] = t2h[ct * 16 + rcol];
        #pragma unroll
        for (int rt = 0; rt < 2; ++rt)
            #pragma unroll
            for (int ct = 0; ct < 4; ++ct)
                #pragma unroll
                for (int reg = 0; reg < 4; ++reg) {
                    float d2 = x2r[rt][reg] + th[ct] - 2.f * acc[rt][ct][reg];
                    int qrow = qBase + w * 32 + rt * 16 + rquad * 4 + reg;
                    int col = sBase + ct * 16 + rcol;
                    dsub[(size_t)qrow * S_PAD + col] = __float2half_rn(d2);
                }
    }
}

// ---------------------------------------------------------------------------
// Kernel 2: tau[q] = 16th-smallest value of dsub row q (values only).
// Barrier-free per-wave tournament + 64-wide rank merge.
__global__ __launch_bounds__(256)
void knn_select(const __half* __restrict__ dsub, float* __restrict__ tau) {
    __shared__ float wk[64];
    int q = blockIdx.x, tid = threadIdx.x;
    int w = tid >> 6, lane = tid & 63;

    float bd[KNN];
    #pragma unroll
    for (int j = 0; j < KNN; ++j) bd[j] = 3.4e38f;
    for (int k = 0; k < 25; ++k) {
        int idx = k * 256 + tid;
        if (idx < S_PAD) {
            float v = __half2float(dsub[(size_t)q * S_PAD + idx]);
            if (v < bd[KNN - 1]) {
                bd[KNN - 1] = v;
                #pragma unroll
                for (int j = KNN - 1; j >= 1; --j)
                    if (bd[j] < bd[j - 1]) { float t = bd[j]; bd[j] = bd[j - 1]; bd[j - 1] = t; }
            }
        }
    }

    // Per-wave 16-smallest (sorted output), no barriers.
    #pragma unroll 1
    for (int sel = 0; sel < KNN; ++sel) {
        float mv = bd[0]; int ml = lane;
        #pragma unroll
        for (int off = 32; off > 0; off >>= 1) {
            float ov = __shfl_down(mv, off, 64);
            int   ol = __shfl_down(ml, off, 64);
            if (ov < mv || (ov == mv && ol < ml)) { mv = ov; ml = ol; }
        }
        mv = __shfl(mv, 0, 64);
        ml = __shfl(ml, 0, 64);
        if (lane == 0) wk[w * KNN + sel] = mv;
        if (lane == ml) {
            #pragma unroll
            for (int j = 0; j < KNN - 1; ++j) bd[j] = bd[j + 1];
            bd[KNN - 1] = 3.4e38f;
        }
    }
    __syncthreads();
    // Rank merge of 4 sorted 16-lists -> exact 16th smallest value.
    if (tid < 64) {
        float v = wk[tid];
        int rank = 0;
        #pragma unroll 8
        for (int j = 0; j < 64; ++j) {
            float u = wk[j];
            if (u < v || (u == v && j < tid)) ++rank;
        }
        if (rank == KNN - 1) tau[q] = v;
    }
}

// ---------------------------------------------------------------------------
// Kernel 3: fp32 -> bf16 conversion of one train half (pad rows zero-filled).
// Train rows get the 16-byte-granule XOR swizzle baked into the WRITE so the
// filter's linear global_load_lds lands the swizzled layout in LDS.
// h0 launch carries 256 extra blocks that convert the 2048 query rows into a
// LINEAR bf16 buffer xb.
__global__ __launch_bounds__(256)
void knn_convert_bf16(const float* __restrict__ train,
                      unsigned int* __restrict__ tb, int rowBase,
                      const float* __restrict__ x,
                      unsigned int* __restrict__ xb) {
    int b = blockIdx.x;
    if (b >= (TBH * 32) / 256) {                   // x-conversion tail (h0 only)
        int i = (b - (TBH * 32) / 256) * 256 + threadIdx.x;   // 65536 threads
        int row = i >> 5, seg = i & 31;
        float4 v = ((const float4*)x)[(size_t)row * (DIM / 4) + seg];
        uint2 p; p.x = pack_bf16(v.x, v.y); p.y = pack_bf16(v.z, v.w);
        ((uint2*)xb)[(size_t)row * 32 + seg] = p;  // linear bf16[2048][128]
        return;
    }
    int i = b * 256 + threadIdx.x;                 // one thread per 4 floats
    int row = i >> 5, seg = i & 31;                // row in [0, TBH)
    int g = rowBase + row;
    float4 v = (g < M_TRAIN)
        ? ((const float4*)train)[(size_t)g * (DIM / 4) + seg]
        : make_float4(0.f, 0.f, 0.f, 0.f);
    uint2 p; p.x = pack_bf16(v.x, v.y); p.y = pack_bf16(v.z, v.w);
    int off = (seg * 8) ^ ((row & 7) << 4);        // swizzled byte offset in row
    *(uint2*)((char*)tb + (size_t)row * 256 + off) = p;
}

// ---------------------------------------------------------------------------
// Kernel 4: one-shot bf16 MFMA filter (64 queries x 128 train rows, K=128).
// Round-11 (= round-10 resubmit; infra failure, never measured):
// SPARSE PER-LANE epilogue. The round-9 epilogue spent ~600 VALU
// insts/thread extracting per-lane fields from wave-uniform ballot words
// (v_lshrrev_b64 storms) to compact ~1.6 passes/wave. Replacement:
//   - build each lane's OWN 8-bit ct-mask during the compare (no ballots)
//   - phase-split: per reg, only lanes with passes issue atomicAdd
//     (4 independent adds -> one round-trip; FEWER executed atomics than
//     the 16 leader-adds of round 9)
//   - statically-unrolled bit-walk stores (static ct -> acc/th stay in regs)
// Same pass condition, same stored values; slot order changes (unordered
// buffers proven since round 2).
__global__ __launch_bounds__(256, 4)
void knn_filter12(const unsigned int* __restrict__ xbb,
                  const short* __restrict__ tbb,
                  const float* __restrict__ t2, const float* __restrict__ x2,
                  const float* __restrict__ tau, int pBase0,
                  int* __restrict__ buf_i, unsigned short* __restrict__ buf_h,
                  int* __restrict__ cnt) {
    __shared__ __align__(16) short T[NTR * DIM];   // 32768 B, single buffer
    int tid = threadIdx.x;
    int w = tid >> 6, lane = tid & 63;
    int rquad = lane >> 4, rcol = lane & 15;

    // XCD-affinity decode (proven): same-tile q-blocks share an XCD.
    int bid = blockIdx.x;
    int xcd = bid & 7, r = bid >> 3;
    int qb = r & 31;
    int nch = xcd + 8 * (r >> 5);          // 0..391, tile index within half
    int qBase = qb * NQT;
    int tbase = pBase0 + nch * NTR;        // global train row base of tile

    // Stage tile: wave w DMAs rows w*32..w*32+31 (8 x 1KB), linear dest.
    const char* gsrc = (const char*)tbb + (size_t)nch * NTR * 256 + w * 8192 + lane * 16;
    char* ldst = (char*)T + w * 8192;
    #pragma unroll
    for (int i = 0; i < 8; ++i)
        gload_lds16(gsrc + i * 1024, ldst + i * 1024);

    // A-frags: direct bf16 loads from xb (overlaps DMA latency).
    bfrag A[4];
    int qrow = qBase + w * 16 + rcol;
    const char* xrow = (const char*)xbb + (size_t)qrow * 256;
    #pragma unroll
    for (int ks = 0; ks < 4; ++ks)
        A[ks] = *(const bfrag*)(xrow + ks * 64 + rquad * 16);

    float RC[4], x2q[4];
    #pragma unroll
    for (int reg = 0; reg < 4; ++reg) {
        int q = qBase + w * 16 + rquad * 4 + reg;
        x2q[reg] = x2[q];
        RC[reg] = 0.5f * (x2q[reg] - tau[q] - MARGIN);
    }
    float th[8];
    #pragma unroll
    for (int ct = 0; ct < 8; ++ct)
        th[ct] = 0.5f * t2[tbase + ct * 16 + rcol];
    __syncthreads();                       // drains DMA (vmcnt) + joins waves

    // Swizzled B reads: row = ct*16+rcol; byte col XOR'd with (rcol&7)<<4.
    int swz = (rcol & 7) << 4;
    int cs[4];
    #pragma unroll
    for (int ks = 0; ks < 4; ++ks)
        cs[ks] = (ks * 64 + rquad * 16) ^ swz;

    const cfrag zero4 = {0.f, 0.f, 0.f, 0.f};
    cfrag acc[8];
    #pragma unroll
    for (int ks = 0; ks < 4; ++ks)
        #pragma unroll
        for (int ct = 0; ct < 8; ++ct) {
            const bfrag B = *(const bfrag*)((const char*)T + (ct * 16 + rcol) * 256 + cs[ks]);
            acc[ct] = (ks == 0)
                ? __builtin_amdgcn_mfma_f32_16x16x32_bf16(A[0], B, zero4, 0, 0, 0)
                : __builtin_amdgcn_mfma_f32_16x16x32_bf16(A[ks], B, acc[ct], 0, 0, 0);
        }

    // ---- Sparse per-lane epilogue ----
    // okm: ct bits whose train row is real (pad only in the very last tile).
    unsigned okm = 0;
    #pragma unroll
    for (int ct = 0; ct < 8; ++ct)
        if (tbase + ct * 16 + rcol < M_TRAIN) okm |= (1u << ct);

    // Per-lane pass masks, one per accumulator row (query).
    unsigned m8[4];
    #pragma unroll
    for (int reg = 0; reg < 4; ++reg) {
        unsigned m = 0;
        #pragma unroll
        for (int ct = 0; ct < 8; ++ct)
            if (acc[ct][reg] >= RC[reg] + th[ct]) m |= (1u << ct);
        m8[reg] = m & okm;
    }

    // Phase 1: independent atomics, only lanes with passes (no result uses).
    int slotR[4];
    #pragma unroll
    for (int reg = 0; reg < 4; ++reg)
        if (m8[reg])
            slotR[reg] = atomicAdd(&cnt[qBase + w * 16 + rquad * 4 + reg],
                                   __popc(m8[reg]));

    // Phase 2: statically-unrolled bit-walk stores (static acc/th indexing).
    #pragma unroll
    for (int reg = 0; reg < 4; ++reg) {
        unsigned m = m8[reg];
        if (m) {
            int q = qBase + w * 16 + rquad * 4 + reg;
            size_t qoff = (size_t)q * CAP;
            int s0 = slotR[reg];
            #pragma unroll
            for (int ct = 0; ct < 8; ++ct)
                if (m & (1u << ct)) {
                    int slot = s0 + __popc(m & ((1u << ct) - 1));
                    if (slot < CAP) {
                        buf_i[qoff + slot] = tbase + ct * 16 + rcol;
                        float d2a = x2q[reg] + 2.f * th[ct] - 2.f * acc[ct][reg];
                        buf_h[qoff + slot] = __half_as_ushort(__float2half_rn(d2a));
                    }
                }
        }
    }
}

// ---------------------------------------------------------------------------
// Kernel 5: approx-pruned exact re-rank + weighted vote.
// Phase A: 16th-smallest approx d2 (per-wave tournament + 64-wide rank merge)
// Phase B: compact candidates with d2a <= kth + SLACK (provably contains the
//          exact top-16 given |d2a - d2| <= MARGIN + fp16 quant)
// Phase C: exact fp32 gather ONLY for kept candidates (4-5x fewer rows)
// Phase D: fully parallel rank-scatter selection (no serial 16-round chain)
__global__ __launch_bounds__(256)
void knn_final(const float* __restrict__ x,
               const float* __restrict__ train,
               const float* __restrict__ t2v,
               const float* __restrict__ x2v,
               const int* __restrict__ buf_i,
               const __half* __restrict__ buf_h,
               const int* __restrict__ cnt,
               const int* __restrict__ labels,
               float* __restrict__ out) {
    __shared__ float sd[CAP];
    __shared__ int   si[CAP];
    __shared__ int   keep[CAP];
    __shared__ float wk[64];
    __shared__ int   kr[KNN];
    __shared__ float sthr;
    __shared__ int   smcnt;
    int q = blockIdx.x;
    int tid = threadIdx.x;
    int w = tid >> 6, lane = tid & 63;
    int grp = lane >> 4, sub = lane & 15;
    int n = cnt[q]; if (n > CAP) n = CAP;
    if (tid == 0) smcnt = 0;
    if (tid < KNN) kr[tid] = -1;

    // ---- Phase A: per-wave 16-smallest approx values over strided 192 ----
    float av[3];
    #pragma unroll
    for (int j = 0; j < 3; ++j) {
        int i = (w * 3 + j) * 64 + lane;
        av[j] = (i < n) ? __half2float(buf_h[(size_t)q * CAP + i]) : 3.4e38f;
    }
    for (int sel = 0; sel < KNN; ++sel) {
        float mv = av[0]; int mc = (lane << 2);
        if (av[1] < mv) { mv = av[1]; mc = (lane << 2) | 1; }
        if (av[2] < mv) { mv = av[2]; mc = (lane << 2) | 2; }
        #pragma unroll
        for (int off = 32; off > 0; off >>= 1) {
            float ov = __shfl_down(mv, off, 64);
            int   oc = __shfl_down(mc, off, 64);
            if (ov < mv || (ov == mv && oc < mc)) { mv = ov; mc = oc; }
        }
        mv = __shfl(mv, 0, 64);
        mc = __shfl(mc, 0, 64);
        if (lane == 0) wk[w * KNN + sel] = mv;
        if (lane == (mc >> 2)) {
            int j0 = mc & 3;
            if (j0 == 0) av[0] = 3.4e38f;
            else if (j0 == 1) av[1] = 3.4e38f;
            else av[2] = 3.4e38f;
        }
    }
    __syncthreads();
    // rank-merge of the 4x16 sorted lists -> global 16th smallest value
    if (tid < 64) {
        float v = wk[tid];
        int rank = 0;
        #pragma unroll 8
        for (int j = 0; j < 64; ++j) {
            float u = wk[j];
            if (u < v || (u == v && j < tid)) ++rank;
        }
        if (rank == KNN - 1) sthr = v + SLACK;
    }
    __syncthreads();
    float thr = sthr;

    // ---- Phase B: compact candidates within the window ----
    for (int i = tid; i < n; i += 256) {
        float h = __half2float(buf_h[(size_t)q * CAP + i]);
        if (h <= thr) {
            int p = atomicAdd(&smcnt, 1);
            keep[p] = buf_i[(size_t)q * CAP + i];
        }
    }
    __syncthreads();
    int m = smcnt;

    // ---- Phase C: exact fp32 distances for kept candidates ----
    const float4* xq = (const float4*)&x[(size_t)q * DIM + sub * 8];
    float4 qa = xq[0], qb = xq[1];
    float x2l = x2v[q];
    for (int base = 0; base < m; base += 16) {
        int i = base + w * 4 + grp;
        if (i < m) {
            int idx = keep[i];
            const float4* tr = (const float4*)&train[(size_t)idx * DIM + sub * 8];
            float4 ta = tr[0], tb4 = tr[1];
            float s = qa.x * ta.x + qa.y * ta.y + qa.z * ta.z + qa.w * ta.w
                    + qb.x * tb4.x + qb.y * tb4.y + qb.z * tb4.z + qb.w * tb4.w;
            s += __shfl_xor(s, 1, 64);
            s += __shfl_xor(s, 2, 64);
            s += __shfl_xor(s, 4, 64);
            s += __shfl_xor(s, 8, 64);
            if (sub == 0) { sd[i] = x2l + t2v[idx] - 2.f * s; si[i] = idx; }
        }
    }
    __syncthreads();

    // ---- Phase D: parallel rank-scatter selection (ranks unique: (d,idx)
    // total order). Each thread ranks its strided elements vs all m. ----
    for (int i = tid; i < m; i += 256) {
        float d = sd[i]; int ix = si[i];
        int rank = 0;
        for (int j = 0; j < m; ++j)
            if (better(sd[j], si[j], d, ix)) ++rank;
        if (rank < KNN) kr[rank] = i;
    }
    __syncthreads();

    // ---- Vote (m >= 16 structurally: all true top-16 pass filter+prune) ----
    if (tid == 0) {
        bool anyzero = false;
        float dist[KNN]; int kidx[KNN];
        #pragma unroll
        for (int j = 0; j < KNN; ++j) {
            int ii = kr[j];
            if (ii >= 0) {
                dist[j] = sqrtf(fmaxf(sd[ii], 0.f));
                kidx[j] = si[ii];
                if (dist[j] == 0.f) anyzero = true;
            } else { dist[j] = -1.f; kidx[j] = -1; }
        }
        float spr[NCLS];
        #pragma unroll
        for (int c = 0; c < NCLS; ++c) spr[c] = 0.f;
        #pragma unroll
        for (int j = 0; j < KNN; ++j) {
            int idxj = kidx[j];
            if (idxj < 0 || idxj >= M_TRAIN) continue;   // sentinel guard
            float wgt = anyzero ? (dist[j] == 0.f ? 1.f : 0.f) : 1.f / dist[j];
            spr[labels[idxj]] += wgt;
        }
        float s = 0.f;
        #pragma unroll
        for (int c = 0; c < NCLS; ++c) s += spr[c];
        if (s == 0.f) s = 1.f;
        float inv = 1.f / s;
        float best = -1.f; int bc = 0;
        #pragma unroll
        for (int c = 0; c < NCLS; ++c) {
            float pv = spr[c] * inv;
            out[NQ + (size_t)q * NCLS + c] = pv;
            if (pv > best) { best = pv; bc = c; }
        }
        out[q] = (float)bc;
    }
}

// ---------------------------------------------------------------------------
extern "C" void kernel_launch(void* const* d_in, const int* in_sizes, int n_in,
                              void* d_out, int out_size, void* d_ws, size_t ws_size,
                              hipStream_t stream) {
    const float* x      = (const float*)d_in[0];
    const float* train  = (const float*)d_in[1];
    const int*   labels = (const int*)d_in[2];
    float* out = (float*)d_out;

    // Byte-exact ws layout, IDENTICAL footprint (26,116,096 B):
    //   t2 401,408 | x2 8,192 | tau 8,192 | cnt 8,192 |
    //   region @425,984: dsub 25,690,112 (dead after knn_select)
    //     -> reused as tb 12,845,056 + buf_i 6,291,456 + xb 524,288
    //        + buf_h 3,145,728 (fp16 approx d2) -> ends at 22,806,528 < dsub end
    char* base = (char*)d_ws;
    float*  t2   = (float*)(base);
    float*  x2   = (float*)(base + 401408);
    float*  tau  = (float*)(base + 409600);
    int*    cnt  = (int*)  (base + 417792);
    char*   region = base + 425984;
    __half* dsub = (__half*)region;                        // 25,690,112 B
    unsigned int* tb = (unsigned int*)region;              // 12,845,056 B (aliases dsub)
    int*    bi   = (int*)(region + 12845056);              //  6,291,456 B
    unsigned int* xb = (unsigned int*)(region + 19136512); //    524,288 B
    __half* bh   = (__half*)(region + 19660800);           //  3,145,728 B

    int nrows = M_TRAIN + NQ;
    knn_norms<<<(nrows * 64 + 255) / 256, 256, 0, stream>>>(train, x, t2, x2, cnt);

    dim3 gs(SCH, NQ / MQ);
    knn_sub_mfma<<<gs, 256, 0, stream>>>(x, train, t2, x2, dsub);

    knn_select<<<NQ, 256, 0, stream>>>(dsub, tau);

    // dsub dead; process the train set in two bf16 halves over its storage.
    // h0's convert also packs x -> xb (256 extra blocks).
    for (int h = 0; h < 2; ++h) {
        int rowBase = h * TBH;
        int cgrid = (TBH * 32) / 256 + (h == 0 ? (NQ * 32) / 256 : 0);
        knn_convert_bf16<<<cgrid, 256, 0, stream>>>(train, tb, rowBase, x, xb);
        knn_filter12<<<(TBH / NTR) * (NQ / NQT), 256, 0, stream>>>(
            xb, (const short*)tb, t2, x2, tau, rowBase, bi, (unsigned short*)bh, cnt);
    }

    knn_final<<<NQ, 256, 0, stream>>>(x, train, t2, x2, bi, bh, cnt, labels, out);
}